// Round 1
// 314.768 us; speedup vs baseline: 1.0906x; 1.0906x over previous
//
#include <hip/hip_runtime.h>
#include <hip/hip_bf16.h>
#include <cstddef>
#include <cstdint>

// Problem dims (fixed by setup_inputs)
#define NB   32
#define LSEQ 1024
#define HDIM 1280
#define PDIM 128
#define KCHUNKS 40  // HDIM / 32

typedef unsigned short ushort_t;
typedef __bf16 bf16x8 __attribute__((ext_vector_type(8)));
typedef float  f32x4  __attribute__((ext_vector_type(4)));

// ws layout (bytes):
//   [0, 128)    : accb (32 floats)
//   [256, ...)  : wB bf16, MFMA-fragment-packed [kc][t][lane][8]
//   [E_OFF,...) : e bf16 [32768][128]
#define WT_OFF  256
#define E_OFF   (256 + HDIM * PDIM * 2)

__device__ __forceinline__ ushort_t bf16_rne(float x) {
  unsigned u = __float_as_uint(x);
  unsigned r = u + 0x7fffu + ((u >> 16) & 1u);
  return (ushort_t)(r >> 16);
}

// ---------------------------------------------------------------------------
// k0: pack w into MFMA-fragment order:
//   wB[((kc*8 + t)*64 + lane)*8 + j] = bf16(w[k][n])
//   with k = kc*32 + lq*8 + j, n = t*16 + lm, lane = lq*16 + lm.
// Each B-fragment load in k1 is then one contiguous 1 KB wave-load.
// Block 0 zeroes accb.
// ---------------------------------------------------------------------------
__global__ __launch_bounds__(256) void k0_wt(const float* __restrict__ pw,
                                             ushort_t* __restrict__ wB,
                                             float* __restrict__ wsf) {
  if (blockIdx.x == 0 && threadIdx.x < 64) wsf[threadIdx.x] = 0.0f;
  const int idx = blockIdx.x * 256 + threadIdx.x;
  const int k = idx >> 7, n = idx & 127;
  const int kc = k >> 5, kr = k & 31;
  const int t = n >> 4, lm = n & 15;
  const int lq = kr >> 3, j = kr & 7;
  const int l = lq * 16 + lm;
  wB[((size_t)(kc * 8 + t) * 64 + l) * 8 + j] = bf16_rne(pw[(size_t)k * PDIM + n]);
}

// ---------------------------------------------------------------------------
// k1: e = normalize(hs @ w + b), bf16 out.  Wave-autonomous MFMA 16x16x32.
// One 64-thread block = one wave = one 16-row tile. NO LDS, NO barriers:
// waves free-run so memory stalls overlap across the 8 resident waves/CU.
//  - A: f32 direct from global (16 rows x 32B/lane contiguous), 4-deep
//    chunk prefetch in registers, converted to bf16 in-register.
//  - B: fragment-packed wB (1 KB coalesced per fragment, L2/L1-hot),
//    2-deep prefetch.
//  - acc: 8 x f32x4 (AGPR). Epilogue: bias + row-norm via 16-lane
//    shfl_xor reduce (same D-fragment mapping as the verified kernel:
//    row = lq*4+r, col = t*16+lm).
// ---------------------------------------------------------------------------
__global__ __launch_bounds__(64, 2) void k1_mfma(const float* __restrict__ hs,
                                                 const ushort_t* __restrict__ wB,
                                                 const float* __restrict__ pb,
                                                 ushort_t* __restrict__ e) {
  const int l = threadIdx.x;          // 0..63
  const int lm = l & 15, lq = l >> 4;
  const int m0 = blockIdx.x * 16;

  const float*    arow  = hs + (size_t)(m0 + lm) * HDIM + lq * 8;
  const ushort_t* bbase = wB + (size_t)l * 8;

  // ---- prologue: A prefetch depth 4, B prefetch depth 2 ----
  float4 Abuf[4][2];
#pragma unroll
  for (int d = 0; d < 4; ++d) {
    Abuf[d][0] = *(const float4*)(arow + d * 32);
    Abuf[d][1] = *(const float4*)(arow + d * 32 + 4);
  }
  bf16x8 Bc[8], Bn[8], Bm[8];
#pragma unroll
  for (int t = 0; t < 8; ++t) {
    Bc[t] = *(const bf16x8*)(bbase + (size_t)(0 * 8 + t) * 512);
    Bn[t] = *(const bf16x8*)(bbase + (size_t)(1 * 8 + t) * 512);
  }

  f32x4 acc[8];
#pragma unroll
  for (int t = 0; t < 8; ++t) acc[t] = (f32x4){0.f, 0.f, 0.f, 0.f};

  // ---- main loop: uniform body (clamped prefetch indices) ----
#pragma unroll 4
  for (int kc = 0; kc < KCHUNKS; ++kc) {
    const int kb = (kc + 2 < KCHUNKS) ? kc + 2 : KCHUNKS - 1;
#pragma unroll
    for (int t = 0; t < 8; ++t)
      Bm[t] = *(const bf16x8*)(bbase + (size_t)(kb * 8 + t) * 512);

    // convert current A stage (read before overwriting the slot)
    union { ushort_t u[8]; bf16x8 v; } cv;
    const float4 f0 = Abuf[kc & 3][0];
    const float4 f1 = Abuf[kc & 3][1];
    cv.u[0] = bf16_rne(f0.x); cv.u[1] = bf16_rne(f0.y);
    cv.u[2] = bf16_rne(f0.z); cv.u[3] = bf16_rne(f0.w);
    cv.u[4] = bf16_rne(f1.x); cv.u[5] = bf16_rne(f1.y);
    cv.u[6] = bf16_rne(f1.z); cv.u[7] = bf16_rne(f1.w);
    const bf16x8 a = cv.v;

    const int ka = (kc + 4 < KCHUNKS) ? kc + 4 : KCHUNKS - 1;
    Abuf[kc & 3][0] = *(const float4*)(arow + ka * 32);
    Abuf[kc & 3][1] = *(const float4*)(arow + ka * 32 + 4);

#pragma unroll
    for (int t = 0; t < 8; ++t)
      acc[t] = __builtin_amdgcn_mfma_f32_16x16x32_bf16(a, Bc[t], acc[t], 0, 0, 0);

#pragma unroll
    for (int t = 0; t < 8; ++t) { Bc[t] = Bn[t]; Bn[t] = Bm[t]; }
  }

  // ---- epilogue: bias + L2-norm per row, bf16 store ----
  float pbv[8];
#pragma unroll
  for (int t = 0; t < 8; ++t) pbv[t] = pb[t * 16 + lm];

#pragma unroll
  for (int r = 0; r < 4; ++r) {
    float v[8];
    float s2 = 0.f;
#pragma unroll
    for (int t = 0; t < 8; ++t) {
      v[t] = acc[t][r] + pbv[t];
      s2 = fmaf(v[t], v[t], s2);
    }
    s2 += __shfl_xor(s2, 1, 64);
    s2 += __shfl_xor(s2, 2, 64);
    s2 += __shfl_xor(s2, 4, 64);
    s2 += __shfl_xor(s2, 8, 64);
    const float inv = 1.0f / sqrtf(s2);
    ushort_t* erow = e + (size_t)(m0 + lq * 4 + r) * PDIM + lm;
#pragma unroll
    for (int t = 0; t < 8; ++t) erow[t * 16] = bf16_rne(v[t] * inv);
  }
}

// ---------------------------------------------------------------------------
// k2: flash-style loss, 32 anchors (2 i-tiles) per block to double compute
// per B-load. 4 waves split the j range; softmax stats accumulate in
// registers off the MFMA C-fragment (|sv| <= 14.3, unshifted exp safe).
// (UNCHANGED this round — isolating the k1 experiment.)
// ---------------------------------------------------------------------------
__global__ __launch_bounds__(256, 3) void k2_loss(const ushort_t* __restrict__ e,
                                                  const int* __restrict__ mask,
                                                  const int* __restrict__ labels,
                                                  float* __restrict__ accb) {
  __shared__ float part[4][32][3];

  const int tid = threadIdx.x;
  const int l = tid & 63, w = tid >> 6;
  const int b  = blockIdx.x >> 5;
  const int i0 = (blockIdx.x & 31) << 5;
  const int lm = l & 15, lq = l >> 4;

  const ushort_t* eb   = e + (size_t)b * LSEQ * PDIM;
  const int*      mrow = mask + b * LSEQ;
  const int*      lrow = labels + b * LSEQ;

  bf16x8 af[2][4];
#pragma unroll
  for (int ii = 0; ii < 2; ++ii) {
    const ushort_t* aptr = eb + (size_t)(i0 + ii * 16 + lm) * PDIM + lq * 8;
#pragma unroll
    for (int c = 0; c < 4; ++c) af[ii][c] = *(const bf16x8*)(aptr + c * 32);
  }

  int  li[2][4], ar[2][4];
  bool vi[2][4];
#pragma unroll
  for (int ii = 0; ii < 2; ++ii)
#pragma unroll
    for (int r = 0; r < 4; ++r) {
      ar[ii][r] = i0 + ii * 16 + lq * 4 + r;
      li[ii][r] = lrow[ar[ii][r]];
      vi[ii][r] = (mrow[ar[ii][r]] != 0) && (li[ii][r] != -100);
    }

  float d[2][4] = {}, ps[2][4] = {}, pc[2][4] = {};
  const float invT = 1.0f / 0.07f;

  // prefetch tile 0
  int jt = w * 16;
  bf16x8 Bc[4];
  int ljc, mjc;
  {
    const int j = jt * 16 + lm;
    const ushort_t* bptr = eb + (size_t)j * PDIM + lq * 8;
#pragma unroll
    for (int c = 0; c < 4; ++c) Bc[c] = *(const bf16x8*)(bptr + c * 32);
    ljc = lrow[j];
    mjc = mrow[j];
  }

#pragma unroll 1
  for (int s = 0; s < 16; ++s, ++jt) {
    bf16x8 Bn[4];
    int ljn = 0, mjn = 0;
    if (s < 15) {
      const int jn = (jt + 1) * 16 + lm;
      const ushort_t* bptr = eb + (size_t)jn * PDIM + lq * 8;
#pragma unroll
      for (int c = 0; c < 4; ++c) Bn[c] = *(const bf16x8*)(bptr + c * 32);
      ljn = lrow[jn];
      mjn = mrow[jn];
    }

    const int j = jt * 16 + lm;
    const bool cvj = (mjc != 0) && (ljc != -100);
#pragma unroll
    for (int ii = 0; ii < 2; ++ii) {
      f32x4 acc = (f32x4){0.f, 0.f, 0.f, 0.f};
#pragma unroll
      for (int c = 0; c < 4; ++c)
        acc = __builtin_amdgcn_mfma_f32_16x16x32_bf16(af[ii][c], Bc[c], acc, 0, 0, 0);
#pragma unroll
      for (int r = 0; r < 4; ++r) {
        const float sv = acc[r] * invT;
        const bool dm  = cvj && (j != ar[ii][r]);
        const float ex = __expf(sv);
        d[ii][r] += dm ? ex : 0.f;
        const bool pos = dm && (ljc == li[ii][r]) && vi[ii][r];
        ps[ii][r] += pos ? sv : 0.f;
        pc[ii][r] += pos ? 1.f : 0.f;
      }
    }

#pragma unroll
    for (int c = 0; c < 4; ++c) Bc[c] = Bn[c];
    ljc = ljn; mjc = mjn;
  }

#pragma unroll
  for (int ii = 0; ii < 2; ++ii)
#pragma unroll
    for (int r = 0; r < 4; ++r) {
#pragma unroll
      for (int off = 1; off < 16; off <<= 1) {
        d[ii][r]  += __shfl_xor(d[ii][r], off, 64);
        ps[ii][r] += __shfl_xor(ps[ii][r], off, 64);
        pc[ii][r] += __shfl_xor(pc[ii][r], off, 64);
      }
    }
  if (lm == 0) {
#pragma unroll
    for (int ii = 0; ii < 2; ++ii)
#pragma unroll
      for (int r = 0; r < 4; ++r) {
        part[w][ii * 16 + lq * 4 + r][0] = d[ii][r];
        part[w][ii * 16 + lq * 4 + r][1] = ps[ii][r];
        part[w][ii * 16 + lq * 4 + r][2] = pc[ii][r];
      }
  }
  __syncthreads();

  if (tid < 32) {
    float D = 0.f, P = 0.f, C = 0.f;
#pragma unroll
    for (int w2 = 0; w2 < 4; ++w2) {
      D += part[w2][tid][0];
      P += part[w2][tid][1];
      C += part[w2][tid][2];
    }
    const float logD = logf(D + 1e-12f);
    float al = (P - C * logD) / (C + 1e-12f);
#pragma unroll
    for (int off = 1; off < 32; off <<= 1) al += __shfl_xor(al, off, 64);
    if (tid == 0) atomicAdd(&accb[b], al);
  }
}

// ---------------------------------------------------------------------------
// k3: final scalar, single block (round-0-verified logic, int4 loads).
// ---------------------------------------------------------------------------
__global__ __launch_bounds__(1024) void k3_final(const int* __restrict__ mask,
                                                 const int* __restrict__ labels,
                                                 const float* __restrict__ accb,
                                                 float* __restrict__ out) {
  __shared__ float lossv[NB];
  __shared__ float okv[NB];
  const int t = threadIdx.x;
  const int b = t >> 5, sub = t & 31;

  int cm = 0, cv = 0;
#pragma unroll
  for (int q = 0; q < 8; ++q) {
    const int idx = b * LSEQ + q * 128 + sub * 4;
    const int4 mv = *(const int4*)(mask + idx);
    const int4 lv = *(const int4*)(labels + idx);
    cm += mv.x + mv.y + mv.z + mv.w;
    cv += ((mv.x != 0 && lv.x != -100) ? 1 : 0) +
          ((mv.y != 0 && lv.y != -100) ? 1 : 0) +
          ((mv.z != 0 && lv.z != -100) ? 1 : 0) +
          ((mv.w != 0 && lv.w != -100) ? 1 : 0);
  }
#pragma unroll
  for (int off = 16; off; off >>= 1) {
    cm += __shfl_xor(cm, off, 64);
    cv += __shfl_xor(cv, off, 64);
  }
  if (sub == 0) {
    const bool ok = (cm >= 2);
    lossv[b] = ok ? (-accb[b] / fmaxf((float)cv, 1.0f)) : 0.0f;
    okv[b]   = ok ? 1.0f : 0.0f;
  }
  __syncthreads();
  if (t < NB) {
    float lv = lossv[t], ov = okv[t];
#pragma unroll
    for (int off = 16; off; off >>= 1) {
      lv += __shfl_xor(lv, off, 64);
      ov += __shfl_xor(ov, off, 64);
    }
    if (t == 0) out[0] = lv / fmaxf(ov, 1.0f);
  }
}

// ---------------------------------------------------------------------------
extern "C" void kernel_launch(void* const* d_in, const int* in_sizes, int n_in,
                              void* d_out, int out_size, void* d_ws, size_t ws_size,
                              hipStream_t stream) {
  (void)in_sizes; (void)n_in; (void)out_size; (void)ws_size;
  const float* hs     = (const float*)d_in[0];
  const float* pw     = (const float*)d_in[1];
  const float* pb     = (const float*)d_in[2];
  const int*   mask   = (const int*)d_in[3];
  const int*   labels = (const int*)d_in[4];
  float* out = (float*)d_out;

  char* wsb = (char*)d_ws;
  float*    wsf  = (float*)wsb;
  float*    accb = wsf;  // floats [0,32)
  ushort_t* wB   = (ushort_t*)(wsb + WT_OFF);
  ushort_t* e    = (ushort_t*)(wsb + E_OFF);

  k0_wt<<<(HDIM * PDIM) / 256, 256, 0, stream>>>(pw, wB, wsf);
  k1_mfma<<<(NB * LSEQ) / 16, 64, 0, stream>>>(hs, wB, pb, e);
  k2_loss<<<NB * 32, 256, 0, stream>>>(e, mask, labels, accb);
  k3_final<<<1, 1024, 0, stream>>>(mask, labels, accb, out);
}

// Round 2
// 299.841 us; speedup vs baseline: 1.1449x; 1.0498x over previous
//
#include <hip/hip_runtime.h>
#include <hip/hip_bf16.h>
#include <cstddef>
#include <cstdint>

// Problem dims (fixed by setup_inputs)
#define NB   32
#define LSEQ 1024
#define HDIM 1280
#define PDIM 128
#define KSTEPS 20  // HDIM / 64

typedef unsigned short ushort_t;
typedef __bf16 bf16x8 __attribute__((ext_vector_type(8)));
typedef float  f32x4  __attribute__((ext_vector_type(4)));

// ws layout (bytes):
//   [0, 128)    : accb (32 floats)
//   [256, ...)  : wB bf16, MFMA-fragment-packed [kc][t][lane][8]  (kc = K/32)
//   [E_OFF,...) : e bf16 [32768][128]
#define WT_OFF  256
#define E_OFF   (256 + HDIM * PDIM * 2)

__device__ __forceinline__ ushort_t bf16_rne(float x) {
  unsigned u = __float_as_uint(x);
  unsigned r = u + 0x7fffu + ((u >> 16) & 1u);
  return (ushort_t)(r >> 16);
}

// global -> LDS direct copy, 16 B per lane (linear LDS dest = base + lane*16)
#define GLD_LDS16(gp, lp)                                                      \
  __builtin_amdgcn_global_load_lds(                                            \
      (const __attribute__((address_space(1))) void*)(gp),                     \
      (__attribute__((address_space(3))) void*)(lp), 16, 0, 0)

// ---------------------------------------------------------------------------
// k0: pack w into MFMA-fragment order (UNCHANGED from round 1):
//   wB[((kc*8 + t)*64 + lane)*8 + j] = bf16(w[k][n])
//   with k = kc*32 + lq*8 + j, n = t*16 + lm, lane = lq*16 + lm.
// Block 0 zeroes accb.
// ---------------------------------------------------------------------------
__global__ __launch_bounds__(256) void k0_wt(const float* __restrict__ pw,
                                             ushort_t* __restrict__ wB,
                                             float* __restrict__ wsf) {
  if (blockIdx.x == 0 && threadIdx.x < 64) wsf[threadIdx.x] = 0.0f;
  const int idx = blockIdx.x * 256 + threadIdx.x;
  const int k = idx >> 7, n = idx & 127;
  const int kc = k >> 5, kr = k & 31;
  const int t = n >> 4, lm = n & 15;
  const int lq = kr >> 3, j = kr & 7;
  const int l = lq * 16 + lm;
  wB[((size_t)(kc * 8 + t) * 64 + l) * 8 + j] = bf16_rne(pw[(size_t)k * PDIM + n]);
}

// ---------------------------------------------------------------------------
// k1: e = normalize(hs @ w + b), bf16 out.  2-phase global_load_lds pipeline.
// Block = 256 thr (4 waves), tile 32 M x 128 N, BK = 64, 20 K-steps.
// Grid 1024 -> 4 blocks/CU: barrier drains overlap with other blocks' staging.
//  - A: f32 direct-to-LDS (global_load_lds, 16 B/lane), per-lane global
//    gather -> linear LDS dest in fragment-plane layout:
//      plane p = m*4 + kh*2 + h (1 KB each), slot = lane*16,
//      holding A[m*16 + lm][kh*32 + lq*8 + h*4 .. +3] as f32.
//    ds_read_b128 at lane*16 is conflict-free; f32->bf16 cvt in-register.
//  - B: direct from fragment-packed wB (1 KB coalesced wave-loads, L2-hot),
//    issued BEFORE the stage calls so the MFMA's B-wait (vmcnt<=2) leaves
//    the two stage loads in flight.
//  - LDS 2 x 8 KB double-buffer; one vmcnt-drain + barrier per step
//    (minimal 2-phase template).
// Epilogue: bias + cross-wave row-norm via 512 B LDS partials (aliases the
// dead A buffer), D-frag mapping row = m*16 + lq*4 + r, col = w*32 + tt*16+lm.
// ---------------------------------------------------------------------------
__global__ __launch_bounds__(256, 4) void k1_mfma(const float* __restrict__ hs,
                                                  const ushort_t* __restrict__ wB,
                                                  const float* __restrict__ pb,
                                                  ushort_t* __restrict__ e) {
  __shared__ __align__(16) char smem[2][8192];

  const int tid = threadIdx.x;
  const int l = tid & 63, w = tid >> 6;
  const int lm = l & 15, lq = l >> 4;
  const int m0 = blockIdx.x * 32;

  // ---- per-thread staging descriptors: two 16 B gathers per step ----
  // dest offsets: o0 = w*1024 + l*16 (planes 0..3), o1 = o0 + 4096 (planes 4..7)
  const int o0 = w * 1024 + l * 16;
  const int o1 = o0 + 4096;
  const float* ga0;
  const float* ga1;
  {
    // o -> plane p = o>>10: m = p>>2, kh = (p>>1)&1, h = p&1; lane li = l
    int p = o0 >> 10;
    int row = ((p >> 2) << 4) + lm;
    int kk  = (((p >> 1) & 1) << 5) + (lq << 3) + ((p & 1) << 2);
    ga0 = hs + (size_t)(m0 + row) * HDIM + kk;
    p = o1 >> 10;
    row = ((p >> 2) << 4) + lm;
    kk  = (((p >> 1) & 1) << 5) + (lq << 3) + ((p & 1) << 2);
    ga1 = hs + (size_t)(m0 + row) * HDIM + kk;
  }
  // B fragment base: frag (tt,kh) at step st -> bB + (st*2+kh)*4096 + tt*512
  const ushort_t* bB = wB + (size_t)(w * 2) * 512 + (size_t)l * 8;

  f32x4 acc[2][2];
#pragma unroll
  for (int m = 0; m < 2; ++m)
#pragma unroll
    for (int tt = 0; tt < 2; ++tt) acc[m][tt] = (f32x4){0.f, 0.f, 0.f, 0.f};

  // ---- prologue: stage step 0 into buf 0 ----
  GLD_LDS16(ga0, &smem[0][o0]);
  GLD_LDS16(ga1, &smem[0][o1]);
  ga0 += 64; ga1 += 64;
  __syncthreads();

#pragma unroll 2
  for (int st = 0; st < KSTEPS; ++st) {
    const int cur = st & 1;

    // B fragments first (oldest in vmcnt queue)
    bf16x8 Bf[2][2];
#pragma unroll
    for (int kh = 0; kh < 2; ++kh)
#pragma unroll
      for (int tt = 0; tt < 2; ++tt)
        Bf[tt][kh] =
            *(const bf16x8*)(bB + (size_t)(st * 2 + kh) * 4096 + tt * 512);

    // stage next step into the other buffer
    if (st < KSTEPS - 1) {
      GLD_LDS16(ga0, &smem[cur ^ 1][o0]);
      GLD_LDS16(ga1, &smem[cur ^ 1][o1]);
      ga0 += 64; ga1 += 64;
    }

    // A fragments from LDS (+ f32->bf16 cvt)
    bf16x8 a[2][2];
#pragma unroll
    for (int m = 0; m < 2; ++m)
#pragma unroll
      for (int kh = 0; kh < 2; ++kh) {
        const f32x4 f0 =
            *(const f32x4*)&smem[cur][(m * 4 + kh * 2 + 0) * 1024 + l * 16];
        const f32x4 f1 =
            *(const f32x4*)&smem[cur][(m * 4 + kh * 2 + 1) * 1024 + l * 16];
        union { ushort_t u[8]; bf16x8 v; } cv;
        cv.u[0] = bf16_rne(f0[0]); cv.u[1] = bf16_rne(f0[1]);
        cv.u[2] = bf16_rne(f0[2]); cv.u[3] = bf16_rne(f0[3]);
        cv.u[4] = bf16_rne(f1[0]); cv.u[5] = bf16_rne(f1[1]);
        cv.u[6] = bf16_rne(f1[2]); cv.u[7] = bf16_rne(f1[3]);
        a[m][kh] = cv.v;
      }

#pragma unroll
    for (int m = 0; m < 2; ++m)
#pragma unroll
      for (int tt = 0; tt < 2; ++tt)
#pragma unroll
        for (int kh = 0; kh < 2; ++kh)
          acc[m][tt] = __builtin_amdgcn_mfma_f32_16x16x32_bf16(
              a[m][kh], Bf[tt][kh], acc[m][tt], 0, 0, 0);

    __syncthreads();  // drains stage loads (vmcnt 0) + flips buffer
  }

  // ---- epilogue: bias, cross-wave row-norm, bf16 store ----
  const float pbv0 = pb[w * 32 + lm];
  const float pbv1 = pb[w * 32 + 16 + lm];
#pragma unroll
  for (int m = 0; m < 2; ++m)
#pragma unroll
    for (int r = 0; r < 4; ++r) {
      acc[m][0][r] += pbv0;
      acc[m][1][r] += pbv1;
    }

  float* sp = (float*)smem;  // [4 waves][32 rows] partials (aliases dead A buf)
#pragma unroll
  for (int m = 0; m < 2; ++m)
#pragma unroll
    for (int r = 0; r < 4; ++r) {
      float s2 = acc[m][0][r] * acc[m][0][r] + acc[m][1][r] * acc[m][1][r];
      s2 += __shfl_xor(s2, 1, 64);
      s2 += __shfl_xor(s2, 2, 64);
      s2 += __shfl_xor(s2, 4, 64);
      s2 += __shfl_xor(s2, 8, 64);
      if (lm == 0) sp[w * 32 + m * 16 + lq * 4 + r] = s2;
    }
  __syncthreads();

#pragma unroll
  for (int m = 0; m < 2; ++m)
#pragma unroll
    for (int r = 0; r < 4; ++r) {
      const int row = m * 16 + lq * 4 + r;
      const float tot = sp[row] + sp[32 + row] + sp[64 + row] + sp[96 + row];
      const float inv = 1.0f / sqrtf(tot);
      ushort_t* er = e + (size_t)(m0 + row) * PDIM + w * 32 + lm;
      er[0]  = bf16_rne(acc[m][0][r] * inv);
      er[16] = bf16_rne(acc[m][1][r] * inv);
    }
}

// ---------------------------------------------------------------------------
// k2: flash-style loss, 32 anchors (2 i-tiles) per block to double compute
// per B-load. 4 waves split the j range; softmax stats accumulate in
// registers off the MFMA C-fragment (|sv| <= 14.3, unshifted exp safe).
// (UNCHANGED this round — isolating the k1 experiment.)
// ---------------------------------------------------------------------------
__global__ __launch_bounds__(256, 3) void k2_loss(const ushort_t* __restrict__ e,
                                                  const int* __restrict__ mask,
                                                  const int* __restrict__ labels,
                                                  float* __restrict__ accb) {
  __shared__ float part[4][32][3];

  const int tid = threadIdx.x;
  const int l = tid & 63, w = tid >> 6;
  const int b  = blockIdx.x >> 5;
  const int i0 = (blockIdx.x & 31) << 5;
  const int lm = l & 15, lq = l >> 4;

  const ushort_t* eb   = e + (size_t)b * LSEQ * PDIM;
  const int*      mrow = mask + b * LSEQ;
  const int*      lrow = labels + b * LSEQ;

  bf16x8 af[2][4];
#pragma unroll
  for (int ii = 0; ii < 2; ++ii) {
    const ushort_t* aptr = eb + (size_t)(i0 + ii * 16 + lm) * PDIM + lq * 8;
#pragma unroll
    for (int c = 0; c < 4; ++c) af[ii][c] = *(const bf16x8*)(aptr + c * 32);
  }

  int  li[2][4], ar[2][4];
  bool vi[2][4];
#pragma unroll
  for (int ii = 0; ii < 2; ++ii)
#pragma unroll
    for (int r = 0; r < 4; ++r) {
      ar[ii][r] = i0 + ii * 16 + lq * 4 + r;
      li[ii][r] = lrow[ar[ii][r]];
      vi[ii][r] = (mrow[ar[ii][r]] != 0) && (li[ii][r] != -100);
    }

  float d[2][4] = {}, ps[2][4] = {}, pc[2][4] = {};
  const float invT = 1.0f / 0.07f;

  // prefetch tile 0
  int jt = w * 16;
  bf16x8 Bc[4];
  int ljc, mjc;
  {
    const int j = jt * 16 + lm;
    const ushort_t* bptr = eb + (size_t)j * PDIM + lq * 8;
#pragma unroll
    for (int c = 0; c < 4; ++c) Bc[c] = *(const bf16x8*)(bptr + c * 32);
    ljc = lrow[j];
    mjc = mrow[j];
  }

#pragma unroll 1
  for (int s = 0; s < 16; ++s, ++jt) {
    bf16x8 Bn[4];
    int ljn = 0, mjn = 0;
    if (s < 15) {
      const int jn = (jt + 1) * 16 + lm;
      const ushort_t* bptr = eb + (size_t)jn * PDIM + lq * 8;
#pragma unroll
      for (int c = 0; c < 4; ++c) Bn[c] = *(const bf16x8*)(bptr + c * 32);
      ljn = lrow[jn];
      mjn = mrow[jn];
    }

    const int j = jt * 16 + lm;
    const bool cvj = (mjc != 0) && (ljc != -100);
#pragma unroll
    for (int ii = 0; ii < 2; ++ii) {
      f32x4 acc = (f32x4){0.f, 0.f, 0.f, 0.f};
#pragma unroll
      for (int c = 0; c < 4; ++c)
        acc = __builtin_amdgcn_mfma_f32_16x16x32_bf16(af[ii][c], Bc[c], acc, 0, 0, 0);
#pragma unroll
      for (int r = 0; r < 4; ++r) {
        const float sv = acc[r] * invT;
        const bool dm  = cvj && (j != ar[ii][r]);
        const float ex = __expf(sv);
        d[ii][r] += dm ? ex : 0.f;
        const bool pos = dm && (ljc == li[ii][r]) && vi[ii][r];
        ps[ii][r] += pos ? sv : 0.f;
        pc[ii][r] += pos ? 1.f : 0.f;
      }
    }

#pragma unroll
    for (int c = 0; c < 4; ++c) Bc[c] = Bn[c];
    ljc = ljn; mjc = mjn;
  }

#pragma unroll
  for (int ii = 0; ii < 2; ++ii)
#pragma unroll
    for (int r = 0; r < 4; ++r) {
#pragma unroll
      for (int off = 1; off < 16; off <<= 1) {
        d[ii][r]  += __shfl_xor(d[ii][r], off, 64);
        ps[ii][r] += __shfl_xor(ps[ii][r], off, 64);
        pc[ii][r] += __shfl_xor(pc[ii][r], off, 64);
      }
    }
  if (lm == 0) {
#pragma unroll
    for (int ii = 0; ii < 2; ++ii)
#pragma unroll
      for (int r = 0; r < 4; ++r) {
        part[w][ii * 16 + lq * 4 + r][0] = d[ii][r];
        part[w][ii * 16 + lq * 4 + r][1] = ps[ii][r];
        part[w][ii * 16 + lq * 4 + r][2] = pc[ii][r];
      }
  }
  __syncthreads();

  if (tid < 32) {
    float D = 0.f, P = 0.f, C = 0.f;
#pragma unroll
    for (int w2 = 0; w2 < 4; ++w2) {
      D += part[w2][tid][0];
      P += part[w2][tid][1];
      C += part[w2][tid][2];
    }
    const float logD = logf(D + 1e-12f);
    float al = (P - C * logD) / (C + 1e-12f);
#pragma unroll
    for (int off = 1; off < 32; off <<= 1) al += __shfl_xor(al, off, 64);
    if (tid == 0) atomicAdd(&accb[b], al);
  }
}

// ---------------------------------------------------------------------------
// k3: final scalar, single block (round-0-verified logic, int4 loads).
// ---------------------------------------------------------------------------
__global__ __launch_bounds__(1024) void k3_final(const int* __restrict__ mask,
                                                 const int* __restrict__ labels,
                                                 const float* __restrict__ accb,
                                                 float* __restrict__ out) {
  __shared__ float lossv[NB];
  __shared__ float okv[NB];
  const int t = threadIdx.x;
  const int b = t >> 5, sub = t & 31;

  int cm = 0, cv = 0;
#pragma unroll
  for (int q = 0; q < 8; ++q) {
    const int idx = b * LSEQ + q * 128 + sub * 4;
    const int4 mv = *(const int4*)(mask + idx);
    const int4 lv = *(const int4*)(labels + idx);
    cm += mv.x + mv.y + mv.z + mv.w;
    cv += ((mv.x != 0 && lv.x != -100) ? 1 : 0) +
          ((mv.y != 0 && lv.y != -100) ? 1 : 0) +
          ((mv.z != 0 && lv.z != -100) ? 1 : 0) +
          ((mv.w != 0 && lv.w != -100) ? 1 : 0);
  }
#pragma unroll
  for (int off = 16; off; off >>= 1) {
    cm += __shfl_xor(cm, off, 64);
    cv += __shfl_xor(cv, off, 64);
  }
  if (sub == 0) {
    const bool ok = (cm >= 2);
    lossv[b] = ok ? (-accb[b] / fmaxf((float)cv, 1.0f)) : 0.0f;
    okv[b]   = ok ? 1.0f : 0.0f;
  }
  __syncthreads();
  if (t < NB) {
    float lv = lossv[t], ov = okv[t];
#pragma unroll
    for (int off = 16; off; off >>= 1) {
      lv += __shfl_xor(lv, off, 64);
      ov += __shfl_xor(ov, off, 64);
    }
    if (t == 0) out[0] = lv / fmaxf(ov, 1.0f);
  }
}

// ---------------------------------------------------------------------------
extern "C" void kernel_launch(void* const* d_in, const int* in_sizes, int n_in,
                              void* d_out, int out_size, void* d_ws, size_t ws_size,
                              hipStream_t stream) {
  (void)in_sizes; (void)n_in; (void)out_size; (void)ws_size;
  const float* hs     = (const float*)d_in[0];
  const float* pw     = (const float*)d_in[1];
  const float* pb     = (const float*)d_in[2];
  const int*   mask   = (const int*)d_in[3];
  const int*   labels = (const int*)d_in[4];
  float* out = (float*)d_out;

  char* wsb = (char*)d_ws;
  float*    wsf  = (float*)wsb;
  float*    accb = wsf;  // floats [0,32)
  ushort_t* wB   = (ushort_t*)(wsb + WT_OFF);
  ushort_t* e    = (ushort_t*)(wsb + E_OFF);

  k0_wt<<<(HDIM * PDIM) / 256, 256, 0, stream>>>(pw, wB, wsf);
  k1_mfma<<<(NB * LSEQ) / 32, 256, 0, stream>>>(hs, wB, pb, e);
  k2_loss<<<NB * 32, 256, 0, stream>>>(e, mask, labels, accb);
  k3_final<<<1, 1024, 0, stream>>>(mask, labels, accb, out);
}

// Round 3
// 296.189 us; speedup vs baseline: 1.1590x; 1.0123x over previous
//
#include <hip/hip_runtime.h>
#include <hip/hip_bf16.h>
#include <cstddef>
#include <cstdint>

// Problem dims (fixed by setup_inputs)
#define NB   32
#define LSEQ 1024
#define HDIM 1280
#define PDIM 128
#define KSTEPS 20  // HDIM / 64

typedef unsigned short ushort_t;
typedef __bf16 bf16x8 __attribute__((ext_vector_type(8)));
typedef float  f32x4  __attribute__((ext_vector_type(4)));

// ws layout (bytes):
//   [0, 128)    : accb (32 floats)
//   [256, ...)  : wB bf16, MFMA-fragment-packed [kc][t][lane][8]  (kc = K/32)
//   [E_OFF,...) : e bf16 [32768][128]
#define WT_OFF  256
#define E_OFF   (256 + HDIM * PDIM * 2)

__device__ __forceinline__ ushort_t bf16_rne(float x) {
  unsigned u = __float_as_uint(x);
  unsigned r = u + 0x7fffu + ((u >> 16) & 1u);
  return (ushort_t)(r >> 16);
}

// global -> LDS direct copy, 16 B per lane (linear LDS dest = base + lane*16)
#define GLD_LDS16(gp, lp)                                                      \
  __builtin_amdgcn_global_load_lds(                                            \
      (const __attribute__((address_space(1))) void*)(gp),                     \
      (__attribute__((address_space(3))) void*)(lp), 16, 0, 0)

// counted-wait + barrier, fused so no memory op can cross either
#define WAIT_BAR(N)                                                            \
  asm volatile("s_waitcnt vmcnt(" #N ") lgkmcnt(0)\n\ts_barrier" ::: "memory")

// ---------------------------------------------------------------------------
// k0: pack w into MFMA-fragment order (UNCHANGED):
//   wB[((kc*8 + t)*64 + lane)*8 + j] = bf16(w[k][n])
//   with k = kc*32 + lq*8 + j, n = t*16 + lm, lane = lq*16 + lm.
// Block 0 zeroes accb.
// ---------------------------------------------------------------------------
__global__ __launch_bounds__(256) void k0_wt(const float* __restrict__ pw,
                                             ushort_t* __restrict__ wB,
                                             float* __restrict__ wsf) {
  if (blockIdx.x == 0 && threadIdx.x < 64) wsf[threadIdx.x] = 0.0f;
  const int idx = blockIdx.x * 256 + threadIdx.x;
  const int k = idx >> 7, n = idx & 127;
  const int kc = k >> 5, kr = k & 31;
  const int t = n >> 4, lm = n & 15;
  const int lq = kr >> 3, j = kr & 7;
  const int l = lq * 16 + lm;
  wB[((size_t)(kc * 8 + t) * 64 + l) * 8 + j] = bf16_rne(pw[(size_t)k * PDIM + n]);
}

// ---------------------------------------------------------------------------
// k1: e = normalize(hs @ w + b), bf16 out.
// Counted-vmcnt pipeline (T3/T4): 4 LDS buffers x 8 KB, stage depth 3, ONE
// fused {s_waitcnt vmcnt(N) lgkmcnt(0); s_barrier} per step — the stage
// queue never drains to 0 in the main loop (N=12 steady; 0/4 prologue, 8
// tail; constants safe under arbitrary within-region issue order because
// vmcnt retirement is in-order).
//  - A staging: row-major contiguous — each wave = 4 x 256 B full-line row
//    segments. Chunk-XOR swizzle applied on the GLOBAL source
//    (c_src = c_phys ^ (row&7); linear LDS dest per global_load_lds rules),
//    so fragment ds_read_b128 hits 8 lanes per 4-bank group = phase-minimum
//    (conflict-free-equivalent).
//  - B: fragment-packed wB (1 KB coalesced wave-loads, L2-hot), 1-step
//    register prefetch (Bc/Bn) so the compiler's B-wait leaves stage loads
//    in flight.
//  - 4-buffer rotation safety: buf[(st+3)&3] was last read at step st-1;
//    lgkmcnt(0) before each barrier => all reads done before overwrite.
// Epilogue: bias + cross-wave row-norm via LDS partials (aliases buf0, not
// touched after step 16), D-frag row = m*16+lq*4+r, col = w*32+tt*16+lm.
// ---------------------------------------------------------------------------
__global__ __launch_bounds__(256, 4) void k1_mfma(const float* __restrict__ hs,
                                                  const ushort_t* __restrict__ wB,
                                                  const float* __restrict__ pb,
                                                  ushort_t* __restrict__ e) {
  __shared__ __align__(16) char smem[4][8192];

  const int tid = threadIdx.x;
  const int l = tid & 63, w = tid >> 6;
  const int lm = l & 15, lq = l >> 4;
  const int m0 = blockIdx.x * 32;

  // ---- staging source (row-major contiguous, chunk-XOR pre-swizzled) ----
  const int r0 = tid >> 4;        // rows 0..15 (load0), +16 (load1)
  const int cp = tid & 15;        // physical 16 B chunk within row
  const int cs = cp ^ (r0 & 7);   // source chunk (inverse swizzle; same for r0+16)
  const float* ga0 = hs + (size_t)(m0 + r0) * HDIM + cs * 4;
  const float* ga1 = ga0 + (size_t)16 * HDIM;
  const int d0 = tid * 16, d1 = 4096 + tid * 16;

  // B fragment base: frag (tt,kh) at step st -> bB + (st*2+kh)*4096 + tt*512
  const ushort_t* bB = wB + (size_t)(w * 2) * 512 + (size_t)l * 8;

  f32x4 acc[2][2];
#pragma unroll
  for (int m = 0; m < 2; ++m)
#pragma unroll
    for (int tt = 0; tt < 2; ++tt) acc[m][tt] = (f32x4){0.f, 0.f, 0.f, 0.f};

  // ---- prologue: stage steps 0..2 (3 buffers), B for step 0 ----
  GLD_LDS16(ga0 + 0,   &smem[0][d0]); GLD_LDS16(ga1 + 0,   &smem[0][d1]);
  GLD_LDS16(ga0 + 64,  &smem[1][d0]); GLD_LDS16(ga1 + 64,  &smem[1][d1]);
  GLD_LDS16(ga0 + 128, &smem[2][d0]); GLD_LDS16(ga1 + 128, &smem[2][d1]);

  bf16x8 Bc[2][2], Bn[2][2];
#pragma unroll
  for (int kh = 0; kh < 2; ++kh)
#pragma unroll
    for (int tt = 0; tt < 2; ++tt)
      Bc[tt][kh] = *(const bf16x8*)(bB + (size_t)kh * 4096 + tt * 512);

#pragma unroll
  for (int st = 0; st < KSTEPS; ++st) {
    // counted wait + barrier (one asm: nothing crosses)
    if (st == 0)                 WAIT_BAR(0);
    else if (st == 1)            WAIT_BAR(4);
    else if (st >= KSTEPS - 2)   WAIT_BAR(8);
    else                         WAIT_BAR(12);

    // stage step st+3 (buffer last read at step st-1; reads drained above)
    if (st < KSTEPS - 3) {
      GLD_LDS16(ga0 + (st + 3) * 64, &smem[(st + 3) & 3][d0]);
      GLD_LDS16(ga1 + (st + 3) * 64, &smem[(st + 3) & 3][d1]);
    }

    // B prefetch for step st+1
    if (st < KSTEPS - 1) {
#pragma unroll
      for (int kh = 0; kh < 2; ++kh)
#pragma unroll
        for (int tt = 0; tt < 2; ++tt)
          Bn[tt][kh] = *(const bf16x8*)(bB + (size_t)((st + 1) * 2 + kh) * 4096 +
                                        tt * 512);
    }

    // A fragments from LDS (swizzled read) + f32->bf16 cvt
    const char* buf = smem[st & 3];
    bf16x8 a[2][2];
#pragma unroll
    for (int m = 0; m < 2; ++m)
#pragma unroll
      for (int kh = 0; kh < 2; ++kh) {
        const int base = (m * 16 + lm) * 256;
        const int c0 = ((kh * 8 + lq * 2 + 0) ^ (lm & 7)) * 16;
        const int c1 = ((kh * 8 + lq * 2 + 1) ^ (lm & 7)) * 16;
        const f32x4 f0 = *(const f32x4*)&buf[base + c0];
        const f32x4 f1 = *(const f32x4*)&buf[base + c1];
        union { ushort_t u[8]; bf16x8 v; } cv;
        cv.u[0] = bf16_rne(f0[0]); cv.u[1] = bf16_rne(f0[1]);
        cv.u[2] = bf16_rne(f0[2]); cv.u[3] = bf16_rne(f0[3]);
        cv.u[4] = bf16_rne(f1[0]); cv.u[5] = bf16_rne(f1[1]);
        cv.u[6] = bf16_rne(f1[2]); cv.u[7] = bf16_rne(f1[3]);
        a[m][kh] = cv.v;
      }

#pragma unroll
    for (int m = 0; m < 2; ++m)
#pragma unroll
      for (int tt = 0; tt < 2; ++tt)
#pragma unroll
        for (int kh = 0; kh < 2; ++kh)
          acc[m][tt] = __builtin_amdgcn_mfma_f32_16x16x32_bf16(
              a[m][kh], Bc[tt][kh], acc[m][tt], 0, 0, 0);

#pragma unroll
    for (int kh = 0; kh < 2; ++kh)
#pragma unroll
      for (int tt = 0; tt < 2; ++tt) Bc[tt][kh] = Bn[tt][kh];
  }

  // ---- epilogue: bias, cross-wave row-norm, bf16 store ----
  const float pbv0 = pb[w * 32 + lm];
  const float pbv1 = pb[w * 32 + 16 + lm];
#pragma unroll
  for (int m = 0; m < 2; ++m)
#pragma unroll
    for (int r = 0; r < 4; ++r) {
      acc[m][0][r] += pbv0;
      acc[m][1][r] += pbv1;
    }

  // buf0 not touched after step 16; all waves past barrier 17/18/19 -> safe
  float* sp = (float*)smem;  // [4 waves][32 rows] partial sums of squares
#pragma unroll
  for (int m = 0; m < 2; ++m)
#pragma unroll
    for (int r = 0; r < 4; ++r) {
      float s2 = acc[m][0][r] * acc[m][0][r] + acc[m][1][r] * acc[m][1][r];
      s2 += __shfl_xor(s2, 1, 64);
      s2 += __shfl_xor(s2, 2, 64);
      s2 += __shfl_xor(s2, 4, 64);
      s2 += __shfl_xor(s2, 8, 64);
      if (lm == 0) sp[w * 32 + m * 16 + lq * 4 + r] = s2;
    }
  __syncthreads();

#pragma unroll
  for (int m = 0; m < 2; ++m)
#pragma unroll
    for (int r = 0; r < 4; ++r) {
      const int row = m * 16 + lq * 4 + r;
      const float tot = sp[row] + sp[32 + row] + sp[64 + row] + sp[96 + row];
      const float inv = 1.0f / sqrtf(tot);
      ushort_t* er = e + (size_t)(m0 + row) * PDIM + w * 32 + lm;
      er[0]  = bf16_rne(acc[m][0][r] * inv);
      er[16] = bf16_rne(acc[m][1][r] * inv);
    }
}

// ---------------------------------------------------------------------------
// k2: flash-style loss (UNCHANGED this round — isolating the k1 experiment).
// ---------------------------------------------------------------------------
__global__ __launch_bounds__(256, 3) void k2_loss(const ushort_t* __restrict__ e,
                                                  const int* __restrict__ mask,
                                                  const int* __restrict__ labels,
                                                  float* __restrict__ accb) {
  __shared__ float part[4][32][3];

  const int tid = threadIdx.x;
  const int l = tid & 63, w = tid >> 6;
  const int b  = blockIdx.x >> 5;
  const int i0 = (blockIdx.x & 31) << 5;
  const int lm = l & 15, lq = l >> 4;

  const ushort_t* eb   = e + (size_t)b * LSEQ * PDIM;
  const int*      mrow = mask + b * LSEQ;
  const int*      lrow = labels + b * LSEQ;

  bf16x8 af[2][4];
#pragma unroll
  for (int ii = 0; ii < 2; ++ii) {
    const ushort_t* aptr = eb + (size_t)(i0 + ii * 16 + lm) * PDIM + lq * 8;
#pragma unroll
    for (int c = 0; c < 4; ++c) af[ii][c] = *(const bf16x8*)(aptr + c * 32);
  }

  int  li[2][4], ar[2][4];
  bool vi[2][4];
#pragma unroll
  for (int ii = 0; ii < 2; ++ii)
#pragma unroll
    for (int r = 0; r < 4; ++r) {
      ar[ii][r] = i0 + ii * 16 + lq * 4 + r;
      li[ii][r] = lrow[ar[ii][r]];
      vi[ii][r] = (mrow[ar[ii][r]] != 0) && (li[ii][r] != -100);
    }

  float d[2][4] = {}, ps[2][4] = {}, pc[2][4] = {};
  const float invT = 1.0f / 0.07f;

  // prefetch tile 0
  int jt = w * 16;
  bf16x8 Bc[4];
  int ljc, mjc;
  {
    const int j = jt * 16 + lm;
    const ushort_t* bptr = eb + (size_t)j * PDIM + lq * 8;
#pragma unroll
    for (int c = 0; c < 4; ++c) Bc[c] = *(const bf16x8*)(bptr + c * 32);
    ljc = lrow[j];
    mjc = mrow[j];
  }

#pragma unroll 1
  for (int s = 0; s < 16; ++s, ++jt) {
    bf16x8 Bn[4];
    int ljn = 0, mjn = 0;
    if (s < 15) {
      const int jn = (jt + 1) * 16 + lm;
      const ushort_t* bptr = eb + (size_t)jn * PDIM + lq * 8;
#pragma unroll
      for (int c = 0; c < 4; ++c) Bn[c] = *(const bf16x8*)(bptr + c * 32);
      ljn = lrow[jn];
      mjn = mrow[jn];
    }

    const int j = jt * 16 + lm;
    const bool cvj = (mjc != 0) && (ljc != -100);
#pragma unroll
    for (int ii = 0; ii < 2; ++ii) {
      f32x4 acc = (f32x4){0.f, 0.f, 0.f, 0.f};
#pragma unroll
      for (int c = 0; c < 4; ++c)
        acc = __builtin_amdgcn_mfma_f32_16x16x32_bf16(af[ii][c], Bc[c], acc, 0, 0, 0);
#pragma unroll
      for (int r = 0; r < 4; ++r) {
        const float sv = acc[r] * invT;
        const bool dm  = cvj && (j != ar[ii][r]);
        const float ex = __expf(sv);
        d[ii][r] += dm ? ex : 0.f;
        const bool pos = dm && (ljc == li[ii][r]) && vi[ii][r];
        ps[ii][r] += pos ? sv : 0.f;
        pc[ii][r] += pos ? 1.f : 0.f;
      }
    }

#pragma unroll
    for (int c = 0; c < 4; ++c) Bc[c] = Bn[c];
    ljc = ljn; mjc = mjn;
  }

#pragma unroll
  for (int ii = 0; ii < 2; ++ii)
#pragma unroll
    for (int r = 0; r < 4; ++r) {
#pragma unroll
      for (int off = 1; off < 16; off <<= 1) {
        d[ii][r]  += __shfl_xor(d[ii][r], off, 64);
        ps[ii][r] += __shfl_xor(ps[ii][r], off, 64);
        pc[ii][r] += __shfl_xor(pc[ii][r], off, 64);
      }
    }
  if (lm == 0) {
#pragma unroll
    for (int ii = 0; ii < 2; ++ii)
#pragma unroll
      for (int r = 0; r < 4; ++r) {
        part[w][ii * 16 + lq * 4 + r][0] = d[ii][r];
        part[w][ii * 16 + lq * 4 + r][1] = ps[ii][r];
        part[w][ii * 16 + lq * 4 + r][2] = pc[ii][r];
      }
  }
  __syncthreads();

  if (tid < 32) {
    float D = 0.f, P = 0.f, C = 0.f;
#pragma unroll
    for (int w2 = 0; w2 < 4; ++w2) {
      D += part[w2][tid][0];
      P += part[w2][tid][1];
      C += part[w2][tid][2];
    }
    const float logD = logf(D + 1e-12f);
    float al = (P - C * logD) / (C + 1e-12f);
#pragma unroll
    for (int off = 1; off < 32; off <<= 1) al += __shfl_xor(al, off, 64);
    if (tid == 0) atomicAdd(&accb[b], al);
  }
}

// ---------------------------------------------------------------------------
// k3: final scalar, single block (UNCHANGED).
// ---------------------------------------------------------------------------
__global__ __launch_bounds__(1024) void k3_final(const int* __restrict__ mask,
                                                 const int* __restrict__ labels,
                                                 const float* __restrict__ accb,
                                                 float* __restrict__ out) {
  __shared__ float lossv[NB];
  __shared__ float okv[NB];
  const int t = threadIdx.x;
  const int b = t >> 5, sub = t & 31;

  int cm = 0, cv = 0;
#pragma unroll
  for (int q = 0; q < 8; ++q) {
    const int idx = b * LSEQ + q * 128 + sub * 4;
    const int4 mv = *(const int4*)(mask + idx);
    const int4 lv = *(const int4*)(labels + idx);
    cm += mv.x + mv.y + mv.z + mv.w;
    cv += ((mv.x != 0 && lv.x != -100) ? 1 : 0) +
          ((mv.y != 0 && lv.y != -100) ? 1 : 0) +
          ((mv.z != 0 && lv.z != -100) ? 1 : 0) +
          ((mv.w != 0 && lv.w != -100) ? 1 : 0);
  }
#pragma unroll
  for (int off = 16; off; off >>= 1) {
    cm += __shfl_xor(cm, off, 64);
    cv += __shfl_xor(cv, off, 64);
  }
  if (sub == 0) {
    const bool ok = (cm >= 2);
    lossv[b] = ok ? (-accb[b] / fmaxf((float)cv, 1.0f)) : 0.0f;
    okv[b]   = ok ? 1.0f : 0.0f;
  }
  __syncthreads();
  if (t < NB) {
    float lv = lossv[t], ov = okv[t];
#pragma unroll
    for (int off = 16; off; off >>= 1) {
      lv += __shfl_xor(lv, off, 64);
      ov += __shfl_xor(ov, off, 64);
    }
    if (t == 0) out[0] = lv / fmaxf(ov, 1.0f);
  }
}

// ---------------------------------------------------------------------------
extern "C" void kernel_launch(void* const* d_in, const int* in_sizes, int n_in,
                              void* d_out, int out_size, void* d_ws, size_t ws_size,
                              hipStream_t stream) {
  (void)in_sizes; (void)n_in; (void)out_size; (void)ws_size;
  const float* hs     = (const float*)d_in[0];
  const float* pw     = (const float*)d_in[1];
  const float* pb     = (const float*)d_in[2];
  const int*   mask   = (const int*)d_in[3];
  const int*   labels = (const int*)d_in[4];
  float* out = (float*)d_out;

  char* wsb = (char*)d_ws;
  float*    wsf  = (float*)wsb;
  float*    accb = wsf;  // floats [0,32)
  ushort_t* wB   = (ushort_t*)(wsb + WT_OFF);
  ushort_t* e    = (ushort_t*)(wsb + E_OFF);

  k0_wt<<<(HDIM * PDIM) / 256, 256, 0, stream>>>(pw, wB, wsf);
  k1_mfma<<<(NB * LSEQ) / 32, 256, 0, stream>>>(hs, wB, pb, e);
  k2_loss<<<NB * 32, 256, 0, stream>>>(e, mask, labels, accb);
  k3_final<<<1, 1024, 0, stream>>>(mask, labels, accb, out);
}